// Round 5
// baseline (4069.489 us; speedup 1.0000x reference)
//
#include <hip/hip_runtime.h>
#include <hip/hip_bf16.h>
#include <hip/hip_fp16.h>
#include <cstdint>
#include <cstddef>

typedef __attribute__((ext_vector_type(4))) float floatx4;
typedef __attribute__((ext_vector_type(8))) short shortx8;
typedef __attribute__((ext_vector_type(2))) __fp16 f16x2;
typedef __attribute__((ext_vector_type(8))) __fp16 halfx8;

#define T_SEQ 512
#define NIN   512
#define BATCH 256
#define HID   256
#define G3    768
#define NC    101

static __device__ __forceinline__ unsigned short f2bf(float f){
  unsigned int u = __float_as_uint(f);
  u += 0x7FFFu + ((u >> 16) & 1u);
  return (unsigned short)(u >> 16);
}

// ---------------- Phase A: xg[b*Tc+tt][n] = x[b, t0+tt, :] . Wih[n, :] + bih[n]
// Output stored fp16 (halves write traffic; gru reads it fp16).
#define BM 128
#define BN 128
#define BK 64
#define LDK 72

__global__ __launch_bounds__(256) void gemm_xg(
    const float* __restrict__ x, const float* __restrict__ Wih,
    const float* __restrict__ bih, __fp16* __restrict__ xg,
    int t0, int tcLog2)
{
  __shared__ unsigned short As[BM*LDK];
  __shared__ unsigned short Bs[BN*LDK];
  const int tid  = threadIdx.x;
  const int bn   = blockIdx.x;   // N fastest: 6 consecutive blocks share one x-tile (L2 reuse)
  const int bm   = blockIdx.y;
  const int w    = tid >> 6;
  const int l    = tid & 63;
  const int lm   = l & 15;
  const int quad = l >> 4;

  const int srow = tid >> 4;
  const int scol = (tid & 15) * 4;
  const int tcMask = (1 << tcLog2) - 1;

  floatx4 acc[2][8];
  #pragma unroll
  for (int mt = 0; mt < 2; ++mt)
    #pragma unroll
    for (int nt = 0; nt < 8; ++nt)
      acc[mt][nt] = (floatx4){0.f, 0.f, 0.f, 0.f};

  for (int kt = 0; kt < NIN / BK; ++kt){
    const int k0 = kt * BK;
    __syncthreads();
    #pragma unroll
    for (int p = 0; p < 8; ++p){
      const int r  = p * 16 + srow;
      const int gm = bm * BM + r;
      const int b  = gm >> tcLog2;
      const int tt = gm & tcMask;
      const float4 xa = *(const float4*)(x + (size_t)(b * T_SEQ + t0 + tt) * NIN + k0 + scol);
      union { unsigned short u[4]; uint2 v; } pa;
      pa.u[0] = f2bf(xa.x); pa.u[1] = f2bf(xa.y); pa.u[2] = f2bf(xa.z); pa.u[3] = f2bf(xa.w);
      *(uint2*)&As[r * LDK + scol] = pa.v;
      const int gn = bn * BN + r;
      const float4 wb = *(const float4*)(Wih + (size_t)gn * NIN + k0 + scol);
      union { unsigned short u[4]; uint2 v; } pb;
      pb.u[0] = f2bf(wb.x); pb.u[1] = f2bf(wb.y); pb.u[2] = f2bf(wb.z); pb.u[3] = f2bf(wb.w);
      *(uint2*)&Bs[r * LDK + scol] = pb.v;
    }
    __syncthreads();
    #pragma unroll
    for (int ks = 0; ks < 2; ++ks){
      const int kk = ks * 32 + quad * 8;
      shortx8 af[2], bfr[8];
      #pragma unroll
      for (int mt = 0; mt < 2; ++mt)
        af[mt] = *(const shortx8*)&As[(w * 32 + mt * 16 + lm) * LDK + kk];
      #pragma unroll
      for (int nt = 0; nt < 8; ++nt)
        bfr[nt] = *(const shortx8*)&Bs[(nt * 16 + lm) * LDK + kk];
      #pragma unroll
      for (int mt = 0; mt < 2; ++mt)
        #pragma unroll
        for (int nt = 0; nt < 8; ++nt)
          acc[mt][nt] = __builtin_amdgcn_mfma_f32_16x16x32_bf16(af[mt], bfr[nt], acc[mt][nt], 0, 0, 0);
    }
  }

  #pragma unroll
  for (int mt = 0; mt < 2; ++mt){
    #pragma unroll
    for (int nt = 0; nt < 8; ++nt){
      #pragma unroll
      for (int i = 0; i < 4; ++i){
        const int ml = w * 32 + mt * 16 + quad * 4 + i;
        const int nl = nt * 16 + lm;
        const int gm = bm * BM + ml;
        const int gn = bn * BN + nl;
        xg[(size_t)gm * G3 + gn] = (__fp16)(acc[mt][nt][i] + bih[gn]);
      }
    }
  }
}

// ---------------- Phase B: batched-MFMA GRU. 16 batch elements per block,
// 16 blocks. 8 waves; wave w owns j-slice [w*32, w*32+32) for all 3 gates:
// 6 acc tiles of mfma_f32_16x16x32_f16 (M=batch, N=j, K=256 in 8 steps).
// W_hh f16 fragments resident in VGPRs (192/thread = 384 KB/CU).
// h: f32 state in regs; f16 mirror in LDS, double-buffered, XOR-swizzled
// (half-index k ^ ((row&7)<<3)) so A-frag ds_read_b128 is bank-spread.
// Bias folded into acc init. One barrier per step.
#define BB 16

__global__ __launch_bounds__(512, 2) void gru_mfma(
    const __fp16* __restrict__ xg, const float* __restrict__ Whh,
    const float* __restrict__ bhh, float* __restrict__ hstate, int Tc)
{
  __shared__ __align__(16) __fp16 hls[2][BB * HID];
  const int tid = threadIdx.x;
  const int w   = tid >> 6;        // wave 0..7
  const int l   = tid & 63;
  const int lm  = l & 15;          // A row (batch) / B col (j) / D col (j)
  const int lq  = l >> 4;          // k-chunk selector; D rows = lq*4+i
  const int bb0 = blockIdx.x * BB;
  const int jb  = w * 32 + lm;     // j for js=0; js=1 adds +16
  const int hswz = (lm & 7) << 3;  // A-read swizzle (half units)

  // B-frags: lane l holds W[g*256 + w*32 + js*16 + lm][ks*32 + lq*8 .. +7] (f16)
  halfx8 Bf[3][2][8];
  #pragma unroll
  for (int g = 0; g < 3; ++g)
    #pragma unroll
    for (int js = 0; js < 2; ++js)
      #pragma unroll
      for (int ks = 0; ks < 8; ++ks){
        const float* wp = Whh + (size_t)(g * 256 + w * 32 + js * 16 + lm) * HID + ks * 32 + lq * 8;
        const float4 v0 = *(const float4*)wp;
        const float4 v1 = *(const float4*)(wp + 4);
        union { f16x2 h[4]; halfx8 v; } u;
        u.h[0] = __builtin_amdgcn_cvt_pkrtz(v0.x, v0.y);
        u.h[1] = __builtin_amdgcn_cvt_pkrtz(v0.z, v0.w);
        u.h[2] = __builtin_amdgcn_cvt_pkrtz(v1.x, v1.y);
        u.h[3] = __builtin_amdgcn_cvt_pkrtz(v1.z, v1.w);
        Bf[g][js][ks] = u.v;
      }

  float bias[3][2];
  #pragma unroll
  for (int g = 0; g < 3; ++g){
    bias[g][0] = bhh[g * 256 + jb];
    bias[g][1] = bhh[g * 256 + jb + 16];
  }

  // init h (f32 state in regs + f16 mirror in LDS buf 0)
  float hold[2][4];
  #pragma unroll
  for (int js = 0; js < 2; ++js)
    #pragma unroll
    for (int i = 0; i < 4; ++i){
      const int b = lq * 4 + i;
      const int j = jb + js * 16;
      const float h0 = hstate[(bb0 + b) * HID + j];
      hold[js][i] = h0;
      hls[0][b * HID + (j ^ ((b & 7) << 3))] = (__fp16)h0;
    }

  int rowoff[4];
  #pragma unroll
  for (int i = 0; i < 4; ++i)
    rowoff[i] = ((bb0 + lq * 4 + i) * Tc) * G3 + jb;

  __syncthreads();

  #pragma unroll 1
  for (int t = 0; t < Tc; ++t){
    // xg for this step: 24 u16 loads, issued before the k-loop (latency hidden)
    __fp16 xv[3][2][4];
    #pragma unroll
    for (int i = 0; i < 4; ++i){
      const __fp16* xp = xg + rowoff[i] + t * G3;
      #pragma unroll
      for (int g = 0; g < 3; ++g)
        #pragma unroll
        for (int js = 0; js < 2; ++js)
          xv[g][js][i] = xp[g * 256 + js * 16];
    }

    floatx4 acc[3][2];
    #pragma unroll
    for (int g = 0; g < 3; ++g)
      #pragma unroll
      for (int js = 0; js < 2; ++js)
        acc[g][js] = (floatx4){bias[g][js], bias[g][js], bias[g][js], bias[g][js]};

    const __fp16* hb = &hls[t & 1][0];
    #pragma unroll
    for (int ks = 0; ks < 8; ++ks){
      const int off = (ks * 32 + lq * 8) ^ hswz;
      const halfx8 av = *(const halfx8*)&hb[lm * HID + off];
      #pragma unroll
      for (int g = 0; g < 3; ++g)
        #pragma unroll
        for (int js = 0; js < 2; ++js)
          acc[g][js] = __builtin_amdgcn_mfma_f32_16x16x32_f16(av, Bf[g][js][ks], acc[g][js], 0, 0, 0);
    }

    __fp16* hbn = &hls[(t + 1) & 1][0];
    #pragma unroll
    for (int js = 0; js < 2; ++js)
      #pragma unroll
      for (int i = 0; i < 4; ++i){
        const float ar = acc[0][js][i];
        const float az = acc[1][js][i];
        const float an = acc[2][js][i];
        const float xr = (float)xv[0][js][i];
        const float xz = (float)xv[1][js][i];
        const float xn = (float)xv[2][js][i];
        const float r = 1.f / (1.f + __expf(-(xr + ar)));
        const float z = 1.f / (1.f + __expf(-(xz + az)));
        const float a = xn + r * an;
        const float ex = __expf(-2.f * fabsf(a));
        float n = (1.f - ex) / (1.f + ex);
        n = copysignf(n, a);
        const float hnew = fmaf(z, hold[js][i] - n, n);   // (1-z)*n + z*h
        hold[js][i] = hnew;
        const int b = lq * 4 + i;
        const int j = jb + js * 16;
        hbn[b * HID + (j ^ ((b & 7) << 3))] = (__fp16)hnew;
      }
    __syncthreads();
  }

  #pragma unroll
  for (int js = 0; js < 2; ++js)
    #pragma unroll
    for (int i = 0; i < 4; ++i)
      hstate[(bb0 + lq * 4 + i) * HID + jb + js * 16] = hold[js][i];
}

// ---------------- FC
__global__ __launch_bounds__(128) void fc_kernel(
    const float* __restrict__ hstate, const float* __restrict__ fw,
    const float* __restrict__ fb, float* __restrict__ out)
{
  __shared__ float hs[HID];
  const int b = blockIdx.x;
  const int t = threadIdx.x;
  hs[t]       = hstate[b * HID + t];
  hs[t + 128] = hstate[b * HID + t + 128];
  __syncthreads();
  if (t < NC){
    float acc = fb[t];
    const float4* w4 = (const float4*)(fw + (size_t)t * HID);
    const float4* h4 = (const float4*)hs;
    #pragma unroll
    for (int k = 0; k < 64; ++k){
      const float4 wv = w4[k];
      const float4 hv = h4[k];
      acc += wv.x * hv.x + wv.y * hv.y + wv.z * hv.z + wv.w * hv.w;
    }
    out[b * NC + t] = acc;
  }
}

extern "C" void kernel_launch(void* const* d_in, const int* in_sizes, int n_in,
                              void* d_out, int out_size, void* d_ws, size_t ws_size,
                              hipStream_t stream)
{
  const float* x   = (const float*)d_in[0];
  const float* Wih = (const float*)d_in[1];
  const float* Whh = (const float*)d_in[2];
  const float* bih = (const float*)d_in[3];
  const float* bhh = (const float*)d_in[4];
  const float* fcw = (const float*)d_in[5];
  const float* fcb = (const float*)d_in[6];
  float* out = (float*)d_out;

  float* hst = (float*)d_ws;
  const size_t hBytes = (size_t)BATCH * HID * sizeof(float);
  __fp16* xg = (__fp16*)((char*)d_ws + hBytes);

  const size_t perT = (size_t)BATCH * G3 * sizeof(__fp16);
  const size_t avail = (ws_size > hBytes) ? (ws_size - hBytes) : 0;
  int tcLog2 = 9;
  while (tcLog2 > 0 && perT * ((size_t)1 << tcLog2) > avail) --tcLog2;
  const int Tc = 1 << tcLog2;

  (void)hipMemsetAsync(hst, 0, hBytes, stream);
  for (int t0 = 0; t0 < T_SEQ; t0 += Tc){
    dim3 grid(6, 2 * Tc);
    gemm_xg<<<grid, 256, 0, stream>>>(x, Wih, bih, xg, t0, tcLog2);
    gru_mfma<<<BATCH / BB, 512, 0, stream>>>(xg, Whh, bhh, hst, Tc);
  }
  fc_kernel<<<BATCH, 128, 0, stream>>>(hst, fcw, fcb, out);
}

// Round 7
// 2578.380 us; speedup vs baseline: 1.5783x; 1.5783x over previous
//
#include <hip/hip_runtime.h>
#include <hip/hip_bf16.h>
#include <hip/hip_fp16.h>
#include <cstdint>
#include <cstddef>

typedef __attribute__((ext_vector_type(4))) float floatx4;
typedef __attribute__((ext_vector_type(8))) short shortx8;
typedef __attribute__((ext_vector_type(2))) __fp16 f16x2;
typedef __attribute__((ext_vector_type(8))) __fp16 halfx8;

#define T_SEQ 512
#define NIN   512
#define BATCH 256
#define HID   256
#define G3    768
#define NC    101

static __device__ __forceinline__ unsigned short f2bf(float f){
  unsigned int u = __float_as_uint(f);
  u += 0x7FFFu + ((u >> 16) & 1u);
  return (unsigned short)(u >> 16);
}

// ---------------- Phase A: xg = x . Wih^T + bih (+ bhh folded for r,z gates).
// Output fp16 in a gru-consumer SoA layout: per (bb,tt), 3 planes of 512
// uint4 (one per gru thread); plane u holds that thread's halves e=8u..8u+7,
// where e = i*6 + g*2 + js  (i=batch row in D-frag, g=gate, js=j-subtile).
// gru then reads its 24 per-step values with 3 coalesced dwordx4 loads.
#define BM 128
#define BN 128
#define BK 64
#define LDK 72

__global__ __launch_bounds__(256) void gemm_xg(
    const float* __restrict__ x, const float* __restrict__ Wih,
    const float* __restrict__ bih, const float* __restrict__ bhh,
    __fp16* __restrict__ xg, int t0, int tcLog2)
{
  __shared__ unsigned short As[BM*LDK];
  __shared__ unsigned short Bs[BN*LDK];
  const int tid  = threadIdx.x;
  const int bn   = blockIdx.x;   // N fastest: 6 consecutive blocks share one x-tile (L2 reuse)
  const int bm   = blockIdx.y;
  const int w    = tid >> 6;
  const int l    = tid & 63;
  const int lm   = l & 15;
  const int quad = l >> 4;

  const int srow = tid >> 4;
  const int scol = (tid & 15) * 4;
  const int tcMask = (1 << tcLog2) - 1;

  floatx4 acc[2][8];
  #pragma unroll
  for (int mt = 0; mt < 2; ++mt)
    #pragma unroll
    for (int nt = 0; nt < 8; ++nt)
      acc[mt][nt] = (floatx4){0.f, 0.f, 0.f, 0.f};

  for (int kt = 0; kt < NIN / BK; ++kt){
    const int k0 = kt * BK;
    __syncthreads();
    #pragma unroll
    for (int p = 0; p < 8; ++p){
      const int r  = p * 16 + srow;
      const int gm = bm * BM + r;
      const int b  = gm >> tcLog2;
      const int tt = gm & tcMask;
      const float4 xa = *(const float4*)(x + (size_t)(b * T_SEQ + t0 + tt) * NIN + k0 + scol);
      union { unsigned short u[4]; uint2 v; } pa;
      pa.u[0] = f2bf(xa.x); pa.u[1] = f2bf(xa.y); pa.u[2] = f2bf(xa.z); pa.u[3] = f2bf(xa.w);
      *(uint2*)&As[r * LDK + scol] = pa.v;
      const int gn = bn * BN + r;
      const float4 wb = *(const float4*)(Wih + (size_t)gn * NIN + k0 + scol);
      union { unsigned short u[4]; uint2 v; } pb;
      pb.u[0] = f2bf(wb.x); pb.u[1] = f2bf(wb.y); pb.u[2] = f2bf(wb.z); pb.u[3] = f2bf(wb.w);
      *(uint2*)&Bs[r * LDK + scol] = pb.v;
    }
    __syncthreads();
    #pragma unroll
    for (int ks = 0; ks < 2; ++ks){
      const int kk = ks * 32 + quad * 8;
      shortx8 af[2], bfr[8];
      #pragma unroll
      for (int mt = 0; mt < 2; ++mt)
        af[mt] = *(const shortx8*)&As[(w * 32 + mt * 16 + lm) * LDK + kk];
      #pragma unroll
      for (int nt = 0; nt < 8; ++nt)
        bfr[nt] = *(const shortx8*)&Bs[(nt * 16 + lm) * LDK + kk];
      #pragma unroll
      for (int mt = 0; mt < 2; ++mt)
        #pragma unroll
        for (int nt = 0; nt < 8; ++nt)
          acc[mt][nt] = __builtin_amdgcn_mfma_f32_16x16x32_bf16(af[mt], bfr[nt], acc[mt][nt], 0, 0, 0);
    }
  }

  #pragma unroll
  for (int mt = 0; mt < 2; ++mt){
    #pragma unroll
    for (int i = 0; i < 4; ++i){
      const int ml = w * 32 + mt * 16 + quad * 4 + i;
      const int gm = bm * BM + ml;
      const int b  = gm >> tcLog2;
      const int tt = gm & tcMask;
      const int bb = b >> 4;
      const int brow = b & 15;
      const size_t rowbase = (size_t)(bb * ((tcMask) + 1) + tt) * 12288; // halves per (bb,tt) = 3*512*8
      const int th_part = (brow >> 2) * 16;   // lq_c * 16
      const int ic6 = (brow & 3) * 6;         // i_c * 6
      #pragma unroll
      for (int nt = 0; nt < 8; ++nt){
        const int gn = bn * BN + nt * 16 + lm;
        const int g  = gn >> 8;
        const int jj = gn & 255;
        const int th = (jj >> 5) * 64 + th_part + (jj & 15);
        const int e  = ic6 + g * 2 + ((jj >> 4) & 1);
        float v = acc[mt][nt][i] + bih[gn];
        if (gn < 512) v += bhh[gn];            // fold bhh for r,z gates (exact)
        xg[rowbase + ((size_t)(e >> 3) * 512 + th) * 8 + (e & 7)] = (__fp16)v;
      }
    }
  }
}

// ---------------- Phase B: batched-MFMA GRU, register-budget-fixed.
// 16 batch/block, 16 blocks, 8 waves, j-slice 32/wave, 6 acc tiles of
// mfma_f32_16x16x32_f16. W_hh f16 in 192 VGPRs/thread. Arch-VGPR demand
// ~250 <= 256 (2 waves/SIMD) so NO AGPR split triggers (R5's failure:
// ~276 regs -> 128/128 VGPR/AGPR split -> accvgpr/scratch shuttling).
// xg read as 3 coalesced dwordx4/thread/step (SoA layout from gemm_xg).
// h: f32 state in regs; f16 mirror in LDS, double-buffered, XOR-swizzled.
#define BB 16

__global__ __launch_bounds__(512, 2) void gru_mfma(
    const __fp16* __restrict__ xg, const float* __restrict__ Whh,
    const float* __restrict__ bhh, float* __restrict__ hstate, int Tc)
{
  __shared__ __align__(16) __fp16 hls[2][BB * HID];
  const int tid = threadIdx.x;
  const int w   = tid >> 6;        // wave 0..7
  const int l   = tid & 63;
  const int lm  = l & 15;          // A row (batch) / D col (j)
  const int lq  = l >> 4;          // k-chunk selector; D rows = lq*4+i
  const int bb0 = blockIdx.x * BB;
  const int jb  = w * 32 + lm;     // j for js=0; js=1 adds +16
  const int hswz = (lm & 7) << 3;  // A-read swizzle (half units, keyed on A row)

  // B-frags: lane l holds W[g*256 + w*32 + js*16 + lm][ks*32 + lq*8 .. +7] (f16)
  halfx8 Bf[3][2][8];
  #pragma unroll
  for (int g = 0; g < 3; ++g)
    #pragma unroll
    for (int js = 0; js < 2; ++js)
      #pragma unroll
      for (int ks = 0; ks < 8; ++ks){
        const float* wp = Whh + (size_t)(g * 256 + w * 32 + js * 16 + lm) * HID + ks * 32 + lq * 8;
        const float4 v0 = *(const float4*)wp;
        const float4 v1 = *(const float4*)(wp + 4);
        union { f16x2 h[4]; halfx8 v; } u;
        u.h[0] = __builtin_amdgcn_cvt_pkrtz(v0.x, v0.y);
        u.h[1] = __builtin_amdgcn_cvt_pkrtz(v0.z, v0.w);
        u.h[2] = __builtin_amdgcn_cvt_pkrtz(v1.x, v1.y);
        u.h[3] = __builtin_amdgcn_cvt_pkrtz(v1.z, v1.w);
        Bf[g][js][ks] = u.v;
      }

  // Only n-gate bhh lives here (r,z folded into xg by gemm_xg).
  const float bn0 = bhh[512 + jb];
  const float bn1 = bhh[512 + jb + 16];

  // init h (f32 state in regs + f16 mirror in LDS buf 0)
  float hold[2][4];
  #pragma unroll
  for (int js = 0; js < 2; ++js)
    #pragma unroll
    for (int i = 0; i < 4; ++i){
      const int b = lq * 4 + i;
      const int j = jb + js * 16;
      const float h0 = hstate[(bb0 + b) * HID + j];
      hold[js][i] = h0;
      hls[0][b * HID + (j ^ ((b & 7) << 3))] = (__fp16)h0;
    }

  const uint4* xgv = (const uint4*)xg;
  unsigned xoff = (unsigned)blockIdx.x * (unsigned)Tc * 1536u + (unsigned)tid;

  __syncthreads();

  #pragma unroll 1
  for (int t = 0; t < Tc; ++t){
    // this thread's 24 xg halves: 3 coalesced 16B loads (consumed in epilogue)
    union { uint4 v[3]; __fp16 h[24]; } xu;
    xu.v[0] = xgv[xoff];
    xu.v[1] = xgv[xoff + 512u];
    xu.v[2] = xgv[xoff + 1024u];
    xoff += 1536u;

    floatx4 acc[3][2];
    #pragma unroll
    for (int g = 0; g < 3; ++g)
      #pragma unroll
      for (int js = 0; js < 2; ++js)
        acc[g][js] = (floatx4){0.f, 0.f, 0.f, 0.f};

    const __fp16* hb = &hls[t & 1][0];
    // two base addrs; (ks>>1)*64-half steps fold into ds_read immediates
    const __fp16* p0 = hb + lm * HID + ((lq * 8) ^ hswz);
    const __fp16* p1 = hb + lm * HID + ((32 + lq * 8) ^ hswz);
    #pragma unroll
    for (int ks = 0; ks < 8; ++ks){
      const halfx8 av = *(const halfx8*)(((ks & 1) ? p1 : p0) + (ks >> 1) * 64);
      #pragma unroll
      for (int g = 0; g < 3; ++g)
        #pragma unroll
        for (int js = 0; js < 2; ++js)
          acc[g][js] = __builtin_amdgcn_mfma_f32_16x16x32_f16(av, Bf[g][js][ks], acc[g][js], 0, 0, 0);
    }

    __fp16* hbn = &hls[(t + 1) & 1][0];
    #pragma unroll
    for (int js = 0; js < 2; ++js){
      const float bnj = js ? bn1 : bn0;
      #pragma unroll
      for (int i = 0; i < 4; ++i){
        // e = i*6 + g*2 + js
        const float xr = (float)xu.h[i * 6 + js];
        const float xz = (float)xu.h[i * 6 + 2 + js];
        const float xn = (float)xu.h[i * 6 + 4 + js];
        const float r = 1.f / (1.f + __expf(-(xr + acc[0][js][i])));
        const float z = 1.f / (1.f + __expf(-(xz + acc[1][js][i])));
        const float a = xn + r * (acc[2][js][i] + bnj);
        const float ex = __expf(-2.f * fabsf(a));
        float n = (1.f - ex) / (1.f + ex);
        n = copysignf(n, a);
        const float hnew = fmaf(z, hold[js][i] - n, n);   // (1-z)*n + z*h
        hold[js][i] = hnew;
        const int b = lq * 4 + i;
        const int j = jb + js * 16;
        hbn[b * HID + (j ^ ((b & 7) << 3))] = (__fp16)hnew;
      }
    }
    __syncthreads();
  }

  #pragma unroll
  for (int js = 0; js < 2; ++js)
    #pragma unroll
    for (int i = 0; i < 4; ++i)
      hstate[(bb0 + lq * 4 + i) * HID + jb + js * 16] = hold[js][i];
}

// ---------------- FC
__global__ __launch_bounds__(128) void fc_kernel(
    const float* __restrict__ hstate, const float* __restrict__ fw,
    const float* __restrict__ fb, float* __restrict__ out)
{
  __shared__ float hs[HID];
  const int b = blockIdx.x;
  const int t = threadIdx.x;
  hs[t]       = hstate[b * HID + t];
  hs[t + 128] = hstate[b * HID + t + 128];
  __syncthreads();
  if (t < NC){
    float acc = fb[t];
    const float4* w4 = (const float4*)(fw + (size_t)t * HID);
    const float4* h4 = (const float4*)hs;
    #pragma unroll
    for (int k = 0; k < 64; ++k){
      const float4 wv = w4[k];
      const float4 hv = h4[k];
      acc += wv.x * hv.x + wv.y * hv.y + wv.z * hv.z + wv.w * hv.w;
    }
    out[b * NC + t] = acc;
  }
}

extern "C" void kernel_launch(void* const* d_in, const int* in_sizes, int n_in,
                              void* d_out, int out_size, void* d_ws, size_t ws_size,
                              hipStream_t stream)
{
  const float* x   = (const float*)d_in[0];
  const float* Wih = (const float*)d_in[1];
  const float* Whh = (const float*)d_in[2];
  const float* bih = (const float*)d_in[3];
  const float* bhh = (const float*)d_in[4];
  const float* fcw = (const float*)d_in[5];
  const float* fcb = (const float*)d_in[6];
  float* out = (float*)d_out;

  float* hst = (float*)d_ws;
  const size_t hBytes = (size_t)BATCH * HID * sizeof(float);
  __fp16* xg = (__fp16*)((char*)d_ws + hBytes);

  const size_t perT = (size_t)BATCH * G3 * sizeof(__fp16);
  const size_t avail = (ws_size > hBytes) ? (ws_size - hBytes) : 0;
  int tcLog2 = 9;
  while (tcLog2 > 0 && perT * ((size_t)1 << tcLog2) > avail) --tcLog2;
  const int Tc = 1 << tcLog2;

  (void)hipMemsetAsync(hst, 0, hBytes, stream);
  for (int t0 = 0; t0 < T_SEQ; t0 += Tc){
    dim3 grid(6, 2 * Tc);
    gemm_xg<<<grid, 256, 0, stream>>>(x, Wih, bih, bhh, xg, t0, tcLog2);
    gru_mfma<<<BATCH / BB, 512, 0, stream>>>(xg, Whh, bhh, hst, Tc);
  }
  fc_kernel<<<BATCH, 128, 0, stream>>>(hst, fcw, fcb, out);
}